// Round 7
// baseline (106.493 us; speedup 1.0000x reference)
//
#include <hip/hip_runtime.h>
#include <hip/hip_bf16.h>
#include <cstdint>

#define NB   128
#define CD   64
#define LD   4096
#define KC   100
#define KT   7            // 7 k-tiles of 16 -> 112 padded clusters
#define KR   (KT * 16)    // 112
#define AKP  72           // akl row stride: 144 B rows, keeps b128 reads 16B-aligned
#define LSPLIT 8
#define LCH  (LD / LSPLIT) // 512 l's per block
#define ITERS (LCH / 64)   // 8 inner iters of 64 l

typedef __attribute__((ext_vector_type(8))) short bf16x8;
typedef __attribute__((ext_vector_type(4))) float f32x4;

__device__ __forceinline__ short bfbits(float f) {
    __hip_bfloat16 h = __float2bfloat16(f);
    return *reinterpret_cast<short*>(&h);
}
__device__ __forceinline__ float bffloat(short s) {
    __hip_bfloat16 h = *reinterpret_cast<__hip_bfloat16*>(&s);
    return __bfloat162float(h);
}

// Precompute W fragments (bf16 hi/lo, MFMA A-layout, zero-padded rows) + padded bias.
// wfrag[((t*2+h)*2+s)*64 + lane] = 8 bf16: W[t*16 + (lane&15)][h*32 + (lane>>4)*8 + 0..7]
__global__ void k_prep(const float* __restrict__ w, const float* __restrict__ b,
                       uint4* __restrict__ wfrag, float* __restrict__ b_pad)
{
    const int tid = threadIdx.x;
    if (tid < 128) b_pad[tid] = (tid < KC) ? b[tid] : -1e30f;
    if (tid < 64) {
        const int r16 = tid & 15, gg = tid >> 4;
        for (int t = 0; t < KT; ++t) {
            const int k = t * 16 + r16;
            for (int h = 0; h < 2; ++h) {
                short hi8[8], lo8[8];
                for (int j = 0; j < 8; ++j) {
                    const int c = h * 32 + gg * 8 + j;
                    float v = (k < KC) ? w[k * CD + c] : 0.f;
                    short hb = bfbits(v);
                    hi8[j] = hb;
                    lo8[j] = bfbits(v - bffloat(hb));
                }
                wfrag[((t * 2 + h) * 2 + 0) * 64 + tid] = *reinterpret_cast<uint4*>(hi8);
                wfrag[((t * 2 + h) * 2 + 1) * 64 + tid] = *reinterpret_cast<uint4*>(lo8);
            }
        }
    }
}

// Fused: normalize+logits (MFMA) + softmax + agg (MFMA). x from global with
// cross-iteration register prefetch (T14); asum in f32 register partials.
// LDS = W frags (28.7KB) + akl (16.1KB) + asum_sm (1.8KB) -> 3 blocks/CU.
__global__ __launch_bounds__(256, 3) void k_fused(
    const float* __restrict__ x, const uint4* __restrict__ wfrag,
    const float* __restrict__ b_pad,
    float* __restrict__ agg_pT, float* __restrict__ asum_pT, int n0)
{
    __shared__ __align__(16) __hip_bfloat16 akl[KR][AKP]; // a tile [k][l] (16128 B)
    __shared__ __align__(16) uint4 wlds[KT * 2 * 2 * 64]; // W fragments (28672 B)
    __shared__ float asum_sm[4][KR];                      // per-wave asum (1792 B)

    const int tid  = threadIdx.x;
    const int lane = tid & 63;
    const int wv   = tid >> 6;
    const int lloc = lane & 15;
    const int g    = lane >> 4;

    // one-time: W fragments -> LDS; consumed after the barrier below
    for (int i = tid; i < KT * 2 * 2 * 64; i += 256) wlds[i] = wfrag[i];

    const int nn = blockIdx.x >> 3;
    const int ls = blockIdx.x & 7;
    const int n  = n0 + nn;
    const float* xb = x + (size_t)n * CD * LD + ls * LCH;

    const float4* bp4 = reinterpret_cast<const float4*>(b_pad);

    f32x4 aagg[KT];
#pragma unroll
    for (int mt = 0; mt < KT; ++mt) aagg[mt] = (f32x4){0.f, 0.f, 0.f, 0.f};
    float pasum[KT][4];
#pragma unroll
    for (int t = 0; t < KT; ++t)
#pragma unroll
        for (int r = 0; r < 4; ++r) pasum[t][r] = 0.f;

    const bf16x8* wfp = reinterpret_cast<const bf16x8*>(wlds);
    const int lw = wv * 16 + lloc;    // this lane's l (logits/softmax phase)
    const int cb = wv * 16 + lloc;    // this lane's c (agg phase)

    // prologue: prefetch iter 0's x (16 col floats for logits, 16 row floats for agg)
    float pvc[16];
    float4 pvr0, pvr1, pvr2, pvr3;
    {
        const float* xcol = xb + lw;
#pragma unroll
        for (int j = 0; j < 8; ++j) {
            pvc[j]     = xcol[(size_t)(g * 8 + j) * LD];
            pvc[8 + j] = xcol[(size_t)(32 + g * 8 + j) * LD];
        }
        const float* xrow = xb + (size_t)cb * LD + g * 8;
        pvr0 = *reinterpret_cast<const float4*>(xrow);
        pvr1 = *reinterpret_cast<const float4*>(xrow + 4);
        pvr2 = *reinterpret_cast<const float4*>(xrow + 32);
        pvr3 = *reinterpret_cast<const float4*>(xrow + 36);
    }

    __syncthreads();                  // wlds ready (once)

    for (int it = 0; it < ITERS; ++it) {
        // (1) logits B-frags from prefetched regs + sumsq via shfl
        float ss = 0.f;
        bf16x8 bhi0, blo0, bhi1, blo1;
#pragma unroll
        for (int j = 0; j < 8; ++j) {
            float v0 = pvc[j];
            ss = fmaf(v0, v0, ss);
            short h0 = bfbits(v0);
            bhi0[j] = h0; blo0[j] = bfbits(v0 - bffloat(h0));
            float v1 = pvc[8 + j];
            ss = fmaf(v1, v1, ss);
            short h1 = bfbits(v1);
            bhi1[j] = h1; blo1[j] = bfbits(v1 - bffloat(h1));
        }
        ss += __shfl_xor(ss, 16);
        ss += __shfl_xor(ss, 32);
        const float rn = 1.0f / fmaxf(sqrtf(ss), 1e-12f);

        // (2) logits MFMA (split precision: hh + hl + lh); W frags from LDS
        f32x4 acc[KT];
#pragma unroll
        for (int t = 0; t < KT; ++t) acc[t] = (f32x4){0.f, 0.f, 0.f, 0.f};
#pragma unroll
        for (int t = 0; t < KT; ++t) {
            bf16x8 wh0 = wfp[((t * 2 + 0) * 2 + 0) * 64 + lane];
            bf16x8 wl0 = wfp[((t * 2 + 0) * 2 + 1) * 64 + lane];
            bf16x8 wh1 = wfp[((t * 2 + 1) * 2 + 0) * 64 + lane];
            bf16x8 wl1 = wfp[((t * 2 + 1) * 2 + 1) * 64 + lane];
            acc[t] = __builtin_amdgcn_mfma_f32_16x16x32_bf16(wh0, bhi0, acc[t], 0, 0, 0);
            acc[t] = __builtin_amdgcn_mfma_f32_16x16x32_bf16(wh1, bhi1, acc[t], 0, 0, 0);
            acc[t] = __builtin_amdgcn_mfma_f32_16x16x32_bf16(wh0, blo0, acc[t], 0, 0, 0);
            acc[t] = __builtin_amdgcn_mfma_f32_16x16x32_bf16(wh1, blo1, acc[t], 0, 0, 0);
            acc[t] = __builtin_amdgcn_mfma_f32_16x16x32_bf16(wl0, bhi0, acc[t], 0, 0, 0);
            acc[t] = __builtin_amdgcn_mfma_f32_16x16x32_bf16(wl1, bhi1, acc[t], 0, 0, 0);
        }

        // (3) softmax over k (per l). D: col(l)=lane&15, row(k)=g*4+r (+16t)
        float m = -3.0e38f;
#pragma unroll
        for (int t = 0; t < KT; ++t) {
            float4 bt = bp4[t * 4 + g];        // L1-hot bias reload
            acc[t][0] = fmaf(acc[t][0], rn, bt.x);
            acc[t][1] = fmaf(acc[t][1], rn, bt.y);
            acc[t][2] = fmaf(acc[t][2], rn, bt.z);
            acc[t][3] = fmaf(acc[t][3], rn, bt.w);
            m = fmaxf(m, fmaxf(fmaxf(acc[t][0], acc[t][1]), fmaxf(acc[t][2], acc[t][3])));
        }
        m = fmaxf(m, __shfl_xor(m, 16));
        m = fmaxf(m, __shfl_xor(m, 32));
        float s = 0.f;
#pragma unroll
        for (int t = 0; t < KT; ++t) {
#pragma unroll
            for (int r = 0; r < 4; ++r) {
                float e = __expf(acc[t][r] - m);
                acc[t][r] = e;
                s += e;
            }
        }
        s += __shfl_xor(s, 16);
        s += __shfl_xor(s, 32);
        const float inv = 1.0f / s;
#pragma unroll
        for (int t = 0; t < KT; ++t) {
#pragma unroll
            for (int r = 0; r < 4; ++r) {
                acc[t][r] *= inv;              // a value (f32)
                pasum[t][r] += acc[t][r];      // asum partial, pre-rounding
            }
        }

        __syncthreads();        // (4) prev iter's akl consumers done

        // (5) a -> LDS [k][l] bf16, plain indexing
#pragma unroll
        for (int r = 0; r < 4; ++r) {
#pragma unroll
            for (int t = 0; t < KT; ++t)
                akl[t * 16 + g * 4 + r][lw] = __float2bfloat16(acc[t][r]);
        }

        // (6) issue next iter's logits-column prefetch (consumed next (1))
        if (it + 1 < ITERS) {
            const float* xcol = xb + (it + 1) * 64 + lw;
#pragma unroll
            for (int j = 0; j < 8; ++j) {
                pvc[j]     = xcol[(size_t)(g * 8 + j) * LD];
                pvc[8 + j] = xcol[(size_t)(32 + g * 8 + j) * LD];
            }
        }

        __syncthreads();        // (7) akl ready

        // (8) agg MFMA: build x frags from prefetched rows, then prefetch next rows
        bf16x8 xh0, xl0, xh1, xl1;
        {
            float xv0[8] = {pvr0.x, pvr0.y, pvr0.z, pvr0.w, pvr1.x, pvr1.y, pvr1.z, pvr1.w};
            float xv1[8] = {pvr2.x, pvr2.y, pvr2.z, pvr2.w, pvr3.x, pvr3.y, pvr3.z, pvr3.w};
#pragma unroll
            for (int j = 0; j < 8; ++j) {
                short hb0 = bfbits(xv0[j]);
                xh0[j] = hb0; xl0[j] = bfbits(xv0[j] - bffloat(hb0));
                short hb1 = bfbits(xv1[j]);
                xh1[j] = hb1; xl1[j] = bfbits(xv1[j] - bffloat(hb1));
            }
        }
        if (it + 1 < ITERS) {
            const float* xrow = xb + (size_t)cb * LD + (it + 1) * 64 + g * 8;
            pvr0 = *reinterpret_cast<const float4*>(xrow);
            pvr1 = *reinterpret_cast<const float4*>(xrow + 4);
            pvr2 = *reinterpret_cast<const float4*>(xrow + 32);
            pvr3 = *reinterpret_cast<const float4*>(xrow + 36);
        }
#pragma unroll
        for (int mt = 0; mt < KT; ++mt) {
            bf16x8 af0 = *reinterpret_cast<const bf16x8*>(&akl[mt * 16 + lloc][g * 8]);
            aagg[mt] = __builtin_amdgcn_mfma_f32_16x16x32_bf16(af0, xh0, aagg[mt], 0, 0, 0);
            aagg[mt] = __builtin_amdgcn_mfma_f32_16x16x32_bf16(af0, xl0, aagg[mt], 0, 0, 0);
            bf16x8 af1 = *reinterpret_cast<const bf16x8*>(&akl[mt * 16 + lloc][32 + g * 8]);
            aagg[mt] = __builtin_amdgcn_mfma_f32_16x16x32_bf16(af1, xh1, aagg[mt], 0, 0, 0);
            aagg[mt] = __builtin_amdgcn_mfma_f32_16x16x32_bf16(af1, xl1, aagg[mt], 0, 0, 0);
        }
    }

    // epilogue: asum reduce (over lloc via shfl, over waves via LDS)
#pragma unroll
    for (int t = 0; t < KT; ++t) {
#pragma unroll
        for (int r = 0; r < 4; ++r) {
            float v = pasum[t][r];
            v += __shfl_xor(v, 1);
            v += __shfl_xor(v, 2);
            v += __shfl_xor(v, 4);
            v += __shfl_xor(v, 8);
            if (lloc == 0) asum_sm[wv][t * 16 + g * 4 + r] = v;
        }
    }
    __syncthreads();

    const size_t nls = (size_t)nn * LSPLIT + ls;
    if (tid < KR)
        asum_pT[nls * KR + tid] = asum_sm[0][tid] + asum_sm[1][tid]
                                + asum_sm[2][tid] + asum_sm[3][tid];

    // write agg partials: agg_pT[nls][c][128kpad]
    float* ap = agg_pT + (nls * 64 + cb) * 128 + g * 4;
#pragma unroll
    for (int mt = 0; mt < KT; ++mt)
        *reinterpret_cast<f32x4*>(ap + mt * 16) = aagg[mt];
}

// Final: reduce partials, subtract centroid*asum, intra-norm over C, global L2 norm.
__global__ __launch_bounds__(256, 1) void k_final(
    const float* __restrict__ agg_pT, const float* __restrict__ asum_pT,
    const float* __restrict__ cent, float* __restrict__ out, int n0)
{
    __shared__ float vbuf[KC][65];
    __shared__ float asum_s[KR];
    __shared__ float rn_s[KC];
    __shared__ float red[256];

    const int tid = threadIdx.x;
    const int nn  = blockIdx.x;
    const int n   = n0 + nn;
    const size_t nb8 = (size_t)nn * LSPLIT;

    if (tid < KR) {
        float s = 0.f;
#pragma unroll
        for (int ls = 0; ls < LSPLIT; ++ls)
            s += asum_pT[(nb8 + ls) * KR + tid];
        asum_s[tid] = s;
    }
    __syncthreads();

    for (int idx = tid; idx < 64 * 128; idx += 256) {
        int c = idx >> 7, k = idx & 127;
        if (k < KC) {
            float s = 0.f;
#pragma unroll
            for (int ls = 0; ls < LSPLIT; ++ls)
                s += agg_pT[((nb8 + ls) * 64 + c) * 128 + k];
            vbuf[k][c] = fmaf(-cent[k * CD + c], asum_s[k], s);
        }
    }
    __syncthreads();

    if (tid < KC) {
        float ssq = 0.f;
#pragma unroll 8
        for (int c = 0; c < CD; ++c) {
            float v = vbuf[tid][c];
            ssq = fmaf(v, v, ssq);
        }
        rn_s[tid] = 1.0f / fmaxf(sqrtf(ssq), 1e-12f);
    }
    __syncthreads();

    float gp = 0.f;
    for (int idx = tid; idx < KC * CD; idx += 256) {
        int k = idx >> 6, c = idx & 63;
        float v = vbuf[k][c] * rn_s[k];
        gp = fmaf(v, v, gp);
    }
    red[tid] = gp;
    __syncthreads();
    for (int off = 128; off > 0; off >>= 1) {
        if (tid < off) red[tid] += red[tid + off];
        __syncthreads();
    }
    const float gnorm = 1.0f / fmaxf(sqrtf(red[0]), 1e-12f);

    float* op = out + (size_t)n * (KC * CD);
    for (int idx = tid; idx < KC * CD; idx += 256) {
        int k = idx >> 6, c = idx & 63;
        op[idx] = vbuf[k][c] * rn_s[k] * gnorm;
    }
}

extern "C" void kernel_launch(void* const* d_in, const int* in_sizes, int n_in,
                              void* d_out, int out_size, void* d_ws, size_t ws_size,
                              hipStream_t stream)
{
    const float* x  = (const float*)d_in[0];
    const float* w  = (const float*)d_in[1];
    const float* b  = (const float*)d_in[2];
    const float* ct = (const float*)d_in[3];
    float* out = (float*)d_out;

    char* wsp = (char*)d_ws;
    uint4* wfrag = (uint4*)wsp;                 // 28672 B
    float* b_pad = (float*)(wsp + 28672);       // 512 B
    char* chunk  = wsp + 32768;

    const size_t agg_per_n  = (size_t)LSPLIT * 64 * 128 * 4; // 262144 B
    const size_t asum_per_n = (size_t)LSPLIT * KR * 4;       // 3584 B
    const size_t per_n = agg_per_n + asum_per_n;

    size_t avail = ws_size > 32768 ? ws_size - 32768 : 0;
    int nc = (int)(avail / per_n);
    if (nc < 1) nc = 1;
    if (nc > NB) nc = NB;

    float* agg_pT  = (float*)chunk;
    float* asum_pT = (float*)(chunk + agg_per_n * (size_t)nc);

    k_prep<<<1, 128, 0, stream>>>(w, b, wfrag, b_pad);
    for (int n0 = 0; n0 < NB; n0 += nc) {
        int cn = NB - n0; if (cn > nc) cn = nc;
        k_fused<<<cn * LSPLIT, 256, 0, stream>>>(x, wfrag, b_pad, agg_pT, asum_pT, n0);
        k_final<<<cn, 256, 0, stream>>>(agg_pT, asum_pT, ct, out, n0);
    }
}